// Round 1
// baseline (879.270 us; speedup 1.0000x reference)
//
#include <hip/hip_runtime.h>

#define NPTS 1024
#define DIM 64
#define KNN 16
#define NA 12
#define AH 256

// ---------------- kernel 1: qkv = to_qkv @ feats, stored transposed [c][n][a][d] ----------------
__global__ __launch_bounds__(256) void qkv_kernel(const float* __restrict__ feats,
                                                  const float* __restrict__ to_qkv,
                                                  float* __restrict__ qkvT) {
    __shared__ float tq[64 * 192];   // [i][j] transposed weights
    __shared__ float f[64 * 12];     // [i][a]
    const int n = blockIdx.x;
    const int t = threadIdx.x;
    for (int e = t; e < 192 * 64; e += 256) {
        int j = e >> 6, i = e & 63;
        tq[i * 192 + j] = to_qkv[e];
    }
    for (int e = t; e < 64 * 12; e += 256) {
        int i = e / 12, a = e % 12;
        f[e] = feats[i * (NPTS * NA) + n * NA + a];
    }
    __syncthreads();
    const int d = t & 63, w = t >> 6;
    for (int p = w; p < 36; p += 4) {
        int c = p / 12, a = p % 12;
        float acc = 0.f;
        #pragma unroll 8
        for (int i = 0; i < 64; ++i)
            acc += tq[i * 192 + c * 64 + d] * f[i * 12 + a];
        qkvT[c * (NPTS * NA * DIM) + (n * NA + a) * DIM + d] = acc;
    }
}

// ---------------- kernel 2: KNN (top-16 smallest d2, stable tie-break like lax.top_k) ----------------
__global__ __launch_bounds__(256) void knn_kernel(const float* __restrict__ xyz,
                                                  int* __restrict__ idxout) {
    __shared__ float px[NPTS], py[NPTS], pz[NPTS], d2[NPTS];
    __shared__ float bd[256];
    __shared__ int bi[256];
    const int n = blockIdx.x, t = threadIdx.x;
    for (int m = t; m < NPTS; m += 256) {
        px[m] = xyz[m];
        py[m] = xyz[NPTS + m];
        pz[m] = xyz[2 * NPTS + m];
    }
    __syncthreads();
    const float xn = px[n], yn = py[n], zn = pz[n];
    const float sqn = xn * xn + yn * yn + zn * zn;
    for (int m = t; m < NPTS; m += 256) {
        float xm = px[m], ym = py[m], zm = pz[m];
        float sqm = xm * xm + ym * ym + zm * zm;
        float dot = xn * xm + yn * ym + zn * zm;
        d2[m] = sqn + sqm - 2.f * dot;
    }
    __syncthreads();
    for (int r = 0; r < KNN; ++r) {
        float bestd = 1e30f;
        int besti = 0x7fffffff;
        for (int m = t; m < NPTS; m += 256) {
            float v = d2[m];
            if (v < bestd) { bestd = v; besti = m; }   // ties keep smaller m (ascending scan)
        }
        bd[t] = bestd; bi[t] = besti;
        __syncthreads();
        for (int s = 128; s > 0; s >>= 1) {
            if (t < s) {
                float od = bd[t + s]; int oi = bi[t + s];
                if (od < bd[t] || (od == bd[t] && oi < bi[t])) { bd[t] = od; bi[t] = oi; }
            }
            __syncthreads();
        }
        if (t == 0) {
            idxout[n * KNN + r] = bi[0];
            d2[bi[0]] = 1e30f;
        }
        __syncthreads();
    }
}

// ---------------- kernel 3: main fused per-point attention ----------------
// block per point n; 12 waves, wave w handles anchor a = w.
__global__ __launch_bounds__(768) void attn_main(const float* __restrict__ xyz,
                                                 const float* __restrict__ anchors,
                                                 const float* __restrict__ pos1,
                                                 const float* __restrict__ pos2,
                                                 const float* __restrict__ am1,
                                                 const float* __restrict__ am2,
                                                 const float* __restrict__ qT,
                                                 const float* __restrict__ kT,
                                                 const float* __restrict__ vT,
                                                 const int* __restrict__ nn,
                                                 float* __restrict__ out) {
    __shared__ float W1T[64 * 256];   // [i][j]  = am1[j][i]
    __shared__ float W2T[256 * 64];   // [h][d]  = am2[d][h]
    __shared__ float P2T[64 * 64];    // [h][d]  = pos2[d][h]
    __shared__ float P1[192];         // pos1 [64][3]
    __shared__ int nidx[KNN];
    __shared__ float sbuf[12][64];
    __shared__ float hbuf[12][256];

    const int n = blockIdx.x;
    const int t = threadIdx.x;
    for (int e = t; e < 256 * 64; e += 768) { int j = e >> 6, i = e & 63; W1T[i * 256 + j] = am1[e]; }
    for (int e = t; e < 64 * 256; e += 768) { int dd = e >> 8, h = e & 255; W2T[h * 64 + dd] = am2[e]; }
    for (int e = t; e < 64 * 64; e += 768)  { int dd = e >> 6, h = e & 63; P2T[h * 64 + dd] = pos2[e]; }
    if (t < 192) P1[t] = pos1[t];
    if (t < KNN) nidx[t] = nn[n * KNN + t];
    __syncthreads();

    const int d = t & 63;
    const int w = t >> 6;     // anchor index
    const int a = w;
    float* sw = sbuf[w];
    float* hw = hbuf[w];

    const float xn = xyz[n], yn = xyz[NPTS + n], zn = xyz[2 * NPTS + n];
    const float A00 = anchors[a * 9 + 0], A01 = anchors[a * 9 + 1], A02 = anchors[a * 9 + 2];
    const float A10 = anchors[a * 9 + 3], A11 = anchors[a * 9 + 4], A12 = anchors[a * 9 + 5];
    const float A20 = anchors[a * 9 + 6], A21 = anchors[a * 9 + 7], A22 = anchors[a * 9 + 8];
    const float p10 = P1[d * 3 + 0], p11 = P1[d * 3 + 1], p12 = P1[d * 3 + 2];
    const float qd = qT[(n * NA + a) * DIM + d];

    float simk[KNN], vgk[KNN];

    for (int k = 0; k < KNN; ++k) {
        const int m = nidx[k];
        const float rx = xn - xyz[m];
        const float ry = yn - xyz[NPTS + m];
        const float rz = zn - xyz[2 * NPTS + m];
        const float g0 = A00 * rx + A01 * ry + A02 * rz;
        const float g1 = A10 * rx + A11 * ry + A12 * rz;
        const float g2 = A20 * rx + A21 * ry + A22 * rz;
        // pe1[d] (relu) -> sbuf
        float p = p10 * g0 + p11 * g1 + p12 * g2;
        sw[d] = p > 0.f ? p : 0.f;
        __syncthreads();
        // pe[d] = pos_mlp2 @ pe1
        float pe0 = 0.f, pe1a = 0.f, pe2 = 0.f, pe3 = 0.f;
        for (int h = 0; h < 64; h += 4) {
            pe0 += P2T[(h + 0) * 64 + d] * sw[h + 0];
            pe1a += P2T[(h + 1) * 64 + d] * sw[h + 1];
            pe2 += P2T[(h + 2) * 64 + d] * sw[h + 2];
            pe3 += P2T[(h + 3) * 64 + d] * sw[h + 3];
        }
        const float pe = (pe0 + pe1a) + (pe2 + pe3);
        const float kg = kT[(m * NA + a) * DIM + d];
        const float vv = vT[(m * NA + a) * DIM + d];
        vgk[k] = vv + pe;
        const float s = qd - kg + pe;
        __syncthreads();       // readers of sbuf (pe1) done before overwrite
        sw[d] = s;
        __syncthreads();
        // h = relu(attn_mlp1 @ s): lane computes rows d, d+64, d+128, d+192
        float h0 = 0.f, h1 = 0.f, h2 = 0.f, h3 = 0.f;
        #pragma unroll 4
        for (int i = 0; i < 64; ++i) {
            const float si = sw[i];
            h0 += W1T[i * 256 + d] * si;
            h1 += W1T[i * 256 + 64 + d] * si;
            h2 += W1T[i * 256 + 128 + d] * si;
            h3 += W1T[i * 256 + 192 + d] * si;
        }
        hw[d] = h0 > 0.f ? h0 : 0.f;
        hw[64 + d] = h1 > 0.f ? h1 : 0.f;
        hw[128 + d] = h2 > 0.f ? h2 : 0.f;
        hw[192 + d] = h3 > 0.f ? h3 : 0.f;
        __syncthreads();
        // sim[d] = attn_mlp2 @ h
        float s0 = 0.f, s1 = 0.f, s2 = 0.f, s3 = 0.f;
        #pragma unroll 4
        for (int l = 0; l < 64; ++l) {
            s0 += W2T[l * 64 + d] * hw[l];
            s1 += W2T[(64 + l) * 64 + d] * hw[64 + l];
            s2 += W2T[(128 + l) * 64 + d] * hw[128 + l];
            s3 += W2T[(192 + l) * 64 + d] * hw[192 + l];
        }
        simk[k] = (s0 + s1) + (s2 + s3);
        __syncthreads();       // hbuf/sbuf consumed before next iteration overwrites
    }

    // per-channel softmax over k, then aggregate with vg
    float mx = simk[0];
    #pragma unroll
    for (int k = 1; k < KNN; ++k) mx = fmaxf(mx, simk[k]);
    float den = 0.f, acc = 0.f;
    #pragma unroll
    for (int k = 0; k < KNN; ++k) {
        float e = __expf(simk[k] - mx);
        den += e;
        acc += e * vgk[k];
    }
    out[d * (NPTS * NA) + n * NA + a] = acc / den;
}

extern "C" void kernel_launch(void* const* d_in, const int* in_sizes, int n_in,
                              void* d_out, int out_size, void* d_ws, size_t ws_size,
                              hipStream_t stream) {
    const float* xyz     = (const float*)d_in[0];
    const float* feats   = (const float*)d_in[1];
    const float* anchors = (const float*)d_in[2];
    const float* to_qkv  = (const float*)d_in[3];
    const float* pos1    = (const float*)d_in[4];
    const float* pos2    = (const float*)d_in[5];
    const float* am1     = (const float*)d_in[6];
    const float* am2     = (const float*)d_in[7];
    float* out = (float*)d_out;

    float* ws = (float*)d_ws;
    const int seg = NPTS * NA * DIM;          // 786432
    float* qT = ws;
    float* kT = ws + seg;
    float* vT = ws + 2 * seg;
    int* nn = (int*)(ws + 3 * seg);

    qkv_kernel<<<NPTS, 256, 0, stream>>>(feats, to_qkv, qT);
    knn_kernel<<<NPTS, 256, 0, stream>>>(xyz, nn);
    attn_main<<<NPTS, 768, 0, stream>>>(xyz, anchors, pos1, pos2, am1, am2, qT, kT, vT, nn, out);
}

// Round 2
// 184.351 us; speedup vs baseline: 4.7695x; 4.7695x over previous
//
#include <hip/hip_runtime.h>

#define NPTS 1024
#define DIM 64
#define KNN 16
#define NA 12
#define NCOL 192              // KNN*NA columns per point, col = a*16 + k

typedef __attribute__((ext_vector_type(8))) short bf16x8;
typedef __attribute__((ext_vector_type(4))) float f32x4;

static __device__ inline short f2bf(float x) {            // round-to-nearest-even
    unsigned u = __float_as_uint(x);
    unsigned r = (u + 0x7fff + ((u >> 16) & 1)) >> 16;
    return (short)r;
}
static __device__ inline float bf2f(unsigned short s) {
    return __uint_as_float(((unsigned)s) << 16);
}
static __device__ inline unsigned pk2(float lo, float hi) {
    return (unsigned)(unsigned short)f2bf(lo) | ((unsigned)(unsigned short)f2bf(hi) << 16);
}
static __device__ inline bf16x8 load8_cvt(const float* p) {
    float4 u = *(const float4*)p;
    float4 v = *(const float4*)(p + 4);
    bf16x8 r;
    r[0] = f2bf(u.x); r[1] = f2bf(u.y); r[2] = f2bf(u.z); r[3] = f2bf(u.w);
    r[4] = f2bf(v.x); r[5] = f2bf(v.y); r[6] = f2bf(v.z); r[7] = f2bf(v.w);
    return r;
}

// ---------------- kernel 1: qkv = to_qkv @ feats, stored transposed [c][n][a][d] ----------------
__global__ __launch_bounds__(256) void qkv_kernel(const float* __restrict__ feats,
                                                  const float* __restrict__ to_qkv,
                                                  float* __restrict__ qkvT) {
    __shared__ float tq[64 * 192];
    __shared__ float f[64 * 12];
    const int n = blockIdx.x;
    const int t = threadIdx.x;
    for (int e = t; e < 192 * 64; e += 256) {
        int j = e >> 6, i = e & 63;
        tq[i * 192 + j] = to_qkv[e];
    }
    for (int e = t; e < 64 * 12; e += 256) {
        int i = e / 12, a = e % 12;
        f[e] = feats[i * (NPTS * NA) + n * NA + a];
    }
    __syncthreads();
    const int d = t & 63, w = t >> 6;
    for (int p = w; p < 36; p += 4) {
        int c = p / 12, a = p % 12;
        float acc = 0.f;
        #pragma unroll 8
        for (int i = 0; i < 64; ++i)
            acc += tq[i * 192 + c * 64 + d] * f[i * 12 + a];
        qkvT[c * (NPTS * NA * DIM) + (n * NA + a) * DIM + d] = acc;
    }
}

// ---------------- kernel 2: KNN, shfl-based selection ----------------
__global__ __launch_bounds__(256) void knn_kernel(const float* __restrict__ xyz,
                                                  int* __restrict__ idxout) {
    __shared__ float px[NPTS], py[NPTS], pz[NPTS];
    __shared__ float cd[4];
    __shared__ int ci[4];
    const int n = blockIdx.x, t = threadIdx.x;
    for (int m = t; m < NPTS; m += 256) {
        px[m] = xyz[m];
        py[m] = xyz[NPTS + m];
        pz[m] = xyz[2 * NPTS + m];
    }
    __syncthreads();
    const float xn = px[n], yn = py[n], zn = pz[n];
    const float sqn = xn * xn + yn * yn + zn * zn;
    float dd[4]; int id[4];
    #pragma unroll
    for (int j = 0; j < 4; ++j) {
        int m = t + j * 256;
        float xm = px[m], ym = py[m], zm = pz[m];
        float sqm = xm * xm + ym * ym + zm * zm;
        float dot = xn * xm + yn * ym + zn * zm;
        dd[j] = sqn + sqm - 2.f * dot;
        id[j] = m;
    }
    const int lane = t & 63, w = t >> 6;
    for (int r = 0; r < KNN; ++r) {
        float bd = 1e30f; int bi = 0x7fffffff;
        #pragma unroll
        for (int j = 0; j < 4; ++j)
            if (dd[j] < bd || (dd[j] == bd && id[j] < bi)) { bd = dd[j]; bi = id[j]; }
        #pragma unroll
        for (int mask = 1; mask < 64; mask <<= 1) {
            float od = __shfl_xor(bd, mask);
            int oi = __shfl_xor(bi, mask);
            if (od < bd || (od == bd && oi < bi)) { bd = od; bi = oi; }
        }
        if (lane == 0) { cd[w] = bd; ci[w] = bi; }
        __syncthreads();
        float wd = cd[0]; int wi = ci[0];
        #pragma unroll
        for (int q = 1; q < 4; ++q)
            if (cd[q] < wd || (cd[q] == wd && ci[q] < wi)) { wd = cd[q]; wi = ci[q]; }
        if (t == 0) idxout[n * KNN + r] = wi;
        #pragma unroll
        for (int j = 0; j < 4; ++j)
            if (id[j] == wi) dd[j] = 1e30f;
        __syncthreads();
    }
}

// ---------------- kernel 3: MFMA fused per-point attention ----------------
// Block = 512 threads (8 waves), one point per block.
// Waves: mg = wave>>1 (0..3), ng = wave&1 (0..1); n-tiles nt = ng*6..ng*6+5 (col = a*16+k, nt == a).
__global__ __launch_bounds__(512, 2) void attn_main(const float* __restrict__ xyz,
                                                    const float* __restrict__ anchors,
                                                    const float* __restrict__ pos1,
                                                    const float* __restrict__ pos2,
                                                    const float* __restrict__ am1,
                                                    const float* __restrict__ am2,
                                                    const float* __restrict__ qT,
                                                    const float* __restrict__ kT,
                                                    const float* __restrict__ vT,
                                                    const int* __restrict__ nn,
                                                    float* __restrict__ out) {
    __shared__ __align__(16) unsigned short XbT[NCOL][72];    // pe1T, then X^T [col][k<64]
    __shared__ __align__(16) unsigned short HbT[NCOL][264];   // H^T [col][h<256]
    __shared__ __align__(16) unsigned short vgT[NCOL][66];    // vg [col][d<64]
    __shared__ float relb[KNN][3];
    __shared__ float ab[108];
    __shared__ int nidx[KNN];

    const int n = blockIdx.x;
    const int t = threadIdx.x;
    const int lane = t & 63;
    const int wave = t >> 6;
    const int c16 = lane & 15;
    const int g = lane >> 4;
    const int mg = wave >> 1;   // m-group
    const int ng = wave & 1;    // n-group (6 n-tiles each)

    if (t < 108) ab[t] = anchors[t];
    if (t < KNN) {
        int m = nn[n * KNN + t];
        nidx[t] = m;
        relb[t][0] = xyz[n] - xyz[m];
        relb[t][1] = xyz[NPTS + n] - xyz[NPTS + m];
        relb[t][2] = xyz[2 * NPTS + n] - xyz[2 * NPTS + m];
    }

    // ---- preload weight A-fragments (registers, whole block lifetime) ----
    bf16x8 w1f[4][2];   // phase A: rows (mg*4+mi)*16+c16, k = kt*32+g*8..
    #pragma unroll
    for (int mi = 0; mi < 4; ++mi)
        #pragma unroll
        for (int kt = 0; kt < 2; ++kt)
            w1f[mi][kt] = load8_cvt(am1 + ((mg * 4 + mi) * 16 + c16) * 64 + kt * 32 + g * 8);
    bf16x8 p2f[2];      // phase 0: rows mg*16+c16
    #pragma unroll
    for (int kt = 0; kt < 2; ++kt)
        p2f[kt] = load8_cvt(pos2 + (mg * 16 + c16) * 64 + kt * 32 + g * 8);
    bf16x8 w2f[8];      // phase B: rows mg*16+c16, K=256
    #pragma unroll
    for (int kt = 0; kt < 8; ++kt)
        w2f[kt] = load8_cvt(am2 + (mg * 16 + c16) * 256 + kt * 32 + g * 8);

    __syncthreads();

    // ---- step 1: pe1 = relu(P1 @ g) -> XbT (transposed) ----
    {
        const int h = t & 63;
        const int cbase = t >> 6;
        const float p10 = pos1[h * 3 + 0], p11 = pos1[h * 3 + 1], p12 = pos1[h * 3 + 2];
        #pragma unroll
        for (int j = 0; j < 24; ++j) {
            int c = cbase + 8 * j;
            int a = c >> 4, k = c & 15;
            float rx = relb[k][0], ry = relb[k][1], rz = relb[k][2];
            float g0 = ab[a * 9 + 0] * rx + ab[a * 9 + 1] * ry + ab[a * 9 + 2] * rz;
            float g1 = ab[a * 9 + 3] * rx + ab[a * 9 + 4] * ry + ab[a * 9 + 5] * rz;
            float g2 = ab[a * 9 + 6] * rx + ab[a * 9 + 7] * ry + ab[a * 9 + 8] * rz;
            float p = p10 * g0 + p11 * g1 + p12 * g2;
            XbT[c][h] = (unsigned short)f2bf(p > 0.f ? p : 0.f);
        }
    }
    __syncthreads();

    const f32x4 zero4 = {0.f, 0.f, 0.f, 0.f};

    // ---- phase 0: pe = P2 @ pe1 (C-layout in regs) ----
    f32x4 peacc[6];
    #pragma unroll
    for (int i = 0; i < 6; ++i) peacc[i] = zero4;
    #pragma unroll
    for (int kt = 0; kt < 2; ++kt) {
        #pragma unroll
        for (int i = 0; i < 6; ++i) {
            int col = (ng * 6 + i) * 16 + c16;
            bf16x8 pb = *(const bf16x8*)&XbT[col][kt * 32 + g * 8];
            peacc[i] = __builtin_amdgcn_mfma_f32_16x16x32_bf16(p2f[kt], pb, peacc[i], 0, 0, 0);
        }
    }

    // ---- step 3: X = q - k_g + pe (regs), vg = v_g + pe -> vgT ----
    float xreg[6][4];
    {
        const int m = nidx[c16];
        #pragma unroll
        for (int i = 0; i < 6; ++i) {
            int a = ng * 6 + i;
            #pragma unroll
            for (int r = 0; r < 4; ++r) {
                int d = mg * 16 + 4 * g + r;
                float pe = peacc[i][r];
                float qv = qT[(n * NA + a) * DIM + d];
                float kg = kT[(m * NA + a) * DIM + d];
                float vv = vT[(m * NA + a) * DIM + d];
                vgT[a * 16 + c16][d] = (unsigned short)f2bf(vv + pe);
                xreg[i][r] = qv - kg + pe;
            }
        }
    }
    __syncthreads();   // all phase-0 reads of XbT done before overwrite
    #pragma unroll
    for (int i = 0; i < 6; ++i) {
        int col = (ng * 6 + i) * 16 + c16;
        int row0 = mg * 16 + 4 * g;
        *(unsigned*)&XbT[col][row0]     = pk2(xreg[i][0], xreg[i][1]);
        *(unsigned*)&XbT[col][row0 + 2] = pk2(xreg[i][2], xreg[i][3]);
    }
    __syncthreads();

    // ---- phase A: H = relu(W1 @ X) -> HbT ----
    {
        f32x4 hacc[4][6];
        #pragma unroll
        for (int mi = 0; mi < 4; ++mi)
            #pragma unroll
            for (int i = 0; i < 6; ++i) hacc[mi][i] = zero4;
        #pragma unroll
        for (int kt = 0; kt < 2; ++kt) {
            bf16x8 xb[6];
            #pragma unroll
            for (int i = 0; i < 6; ++i)
                xb[i] = *(const bf16x8*)&XbT[(ng * 6 + i) * 16 + c16][kt * 32 + g * 8];
            #pragma unroll
            for (int mi = 0; mi < 4; ++mi)
                #pragma unroll
                for (int i = 0; i < 6; ++i)
                    hacc[mi][i] = __builtin_amdgcn_mfma_f32_16x16x32_bf16(w1f[mi][kt], xb[i], hacc[mi][i], 0, 0, 0);
        }
        #pragma unroll
        for (int mi = 0; mi < 4; ++mi) {
            #pragma unroll
            for (int i = 0; i < 6; ++i) {
                int col = (ng * 6 + i) * 16 + c16;
                int hrow = (mg * 4 + mi) * 16 + 4 * g;
                f32x4 v = hacc[mi][i];
                float v0 = v[0] > 0.f ? v[0] : 0.f;
                float v1 = v[1] > 0.f ? v[1] : 0.f;
                float v2 = v[2] > 0.f ? v[2] : 0.f;
                float v3 = v[3] > 0.f ? v[3] : 0.f;
                *(unsigned*)&HbT[col][hrow]     = pk2(v0, v1);
                *(unsigned*)&HbT[col][hrow + 2] = pk2(v2, v3);
            }
        }
    }
    __syncthreads();

    // ---- phase B: S = W2 @ H ----
    f32x4 sacc[6];
    #pragma unroll
    for (int i = 0; i < 6; ++i) sacc[i] = zero4;
    #pragma unroll
    for (int kt = 0; kt < 8; ++kt) {
        bf16x8 hb[6];
        #pragma unroll
        for (int i = 0; i < 6; ++i)
            hb[i] = *(const bf16x8*)&HbT[(ng * 6 + i) * 16 + c16][kt * 32 + g * 8];
        #pragma unroll
        for (int i = 0; i < 6; ++i)
            sacc[i] = __builtin_amdgcn_mfma_f32_16x16x32_bf16(w2f[kt], hb[i], sacc[i], 0, 0, 0);
    }

    // ---- epilogue: per-channel softmax over k (16-lane groups), aggregate ----
    #pragma unroll
    for (int i = 0; i < 6; ++i) {
        int a = ng * 6 + i;
        #pragma unroll
        for (int r = 0; r < 4; ++r) {
            int d = mg * 16 + 4 * g + r;
            float s = sacc[i][r];
            float mx = s;
            #pragma unroll
            for (int mask = 1; mask < 16; mask <<= 1)
                mx = fmaxf(mx, __shfl_xor(mx, mask));
            float e = __expf(s - mx);
            float vg = bf2f(vgT[a * 16 + c16][d]);
            float den = e, num = e * vg;
            #pragma unroll
            for (int mask = 1; mask < 16; mask <<= 1) {
                den += __shfl_xor(den, mask);
                num += __shfl_xor(num, mask);
            }
            if (c16 == 0)
                out[(d * NPTS + n) * NA + a] = num / den;
        }
    }
}

extern "C" void kernel_launch(void* const* d_in, const int* in_sizes, int n_in,
                              void* d_out, int out_size, void* d_ws, size_t ws_size,
                              hipStream_t stream) {
    const float* xyz     = (const float*)d_in[0];
    const float* feats   = (const float*)d_in[1];
    const float* anchors = (const float*)d_in[2];
    const float* to_qkv  = (const float*)d_in[3];
    const float* pos1    = (const float*)d_in[4];
    const float* pos2    = (const float*)d_in[5];
    const float* am1     = (const float*)d_in[6];
    const float* am2     = (const float*)d_in[7];
    float* out = (float*)d_out;

    float* ws = (float*)d_ws;
    const int seg = NPTS * NA * DIM;
    float* qT = ws;
    float* kT = ws + seg;
    float* vT = ws + 2 * seg;
    int* nn = (int*)(ws + 3 * seg);

    qkv_kernel<<<NPTS, 256, 0, stream>>>(feats, to_qkv, qT);
    knn_kernel<<<NPTS, 256, 0, stream>>>(xyz, nn);
    attn_main<<<NPTS, 512, 0, stream>>>(xyz, anchors, pos1, pos2, am1, am2, qT, kT, vT, nn, out);
}

// Round 3
// 94.600 us; speedup vs baseline: 9.2946x; 1.9487x over previous
//
#include <hip/hip_runtime.h>

#define NPTS 1024
#define DIM 64
#define KNN 16
#define NA 12
#define NCOL 192              // KNN*NA columns per point, col = a*16 + k

typedef __attribute__((ext_vector_type(8))) short bf16x8;
typedef __attribute__((ext_vector_type(4))) float f32x4;

static __device__ inline unsigned short f2bfu(float x) {
    __bf16 b = (__bf16)x;                       // hw v_cvt (RNE)
    return __builtin_bit_cast(unsigned short, b);
}
static __device__ inline unsigned pk2(float lo, float hi) {
    return (unsigned)f2bfu(lo) | ((unsigned)f2bfu(hi) << 16);
}
static __device__ inline bf16x8 load8_cvt(const float* p) {
    f32x4 u = *(const f32x4*)p;
    f32x4 v = *(const f32x4*)(p + 4);
    bf16x8 r;
    r[0] = (short)f2bfu(u[0]); r[1] = (short)f2bfu(u[1]); r[2] = (short)f2bfu(u[2]); r[3] = (short)f2bfu(u[3]);
    r[4] = (short)f2bfu(v[0]); r[5] = (short)f2bfu(v[1]); r[6] = (short)f2bfu(v[2]); r[7] = (short)f2bfu(v[3]);
    return r;
}

// ---------------- kernel 1: qkv^T via MFMA + weight frag-packing ----------------
// D[na][cd] = sum_i feats[i][na] * to_qkv[cd][i]; C col = cd -> coalesced stores.
// Grid 256 blocks x 256 thr; block handles 48 na-cols, all 192 cd rows.
__global__ __launch_bounds__(256) void qkv_kernel(const float* __restrict__ feats,
                                                  const float* __restrict__ to_qkv,
                                                  float* __restrict__ qkvT,
                                                  unsigned short* __restrict__ pack,
                                                  const float* __restrict__ pos2,
                                                  const float* __restrict__ am1,
                                                  const float* __restrict__ am2) {
    __shared__ unsigned short XT[48][72];   // feats^T [na][i] bf16
    const int n0 = blockIdx.x * 48;
    const int t = threadIdx.x;
    for (int e = t; e < 48 * 64; e += 256) {
        int c = e % 48, i = e / 48;
        XT[c][i] = f2bfu(feats[i * (NPTS * NA) + n0 + c]);
    }
    __syncthreads();
    const int lane = t & 63, w = t >> 6, c16 = lane & 15, g = lane >> 4;

    bf16x8 bfr[3][2];   // B-frags: to_qkv rows (cd) as cols
    #pragma unroll
    for (int ni = 0; ni < 3; ++ni)
        #pragma unroll
        for (int kt = 0; kt < 2; ++kt) {
            int cd = (w * 3 + ni) * 16 + c16;
            bfr[ni][kt] = load8_cvt(to_qkv + cd * 64 + kt * 32 + g * 8);
        }

    const f32x4 zero4 = {0.f, 0.f, 0.f, 0.f};
    #pragma unroll
    for (int mt = 0; mt < 3; ++mt) {
        f32x4 acc[3] = {zero4, zero4, zero4};
        #pragma unroll
        for (int kt = 0; kt < 2; ++kt) {
            bf16x8 af = *(const bf16x8*)&XT[mt * 16 + c16][kt * 32 + g * 8];
            #pragma unroll
            for (int ni = 0; ni < 3; ++ni)
                acc[ni] = __builtin_amdgcn_mfma_f32_16x16x32_bf16(af, bfr[ni][kt], acc[ni], 0, 0, 0);
        }
        #pragma unroll
        for (int ni = 0; ni < 3; ++ni) {
            int cd = (w * 3 + ni) * 16 + c16;
            int c = cd >> 6, d = cd & 63;
            #pragma unroll
            for (int r = 0; r < 4; ++r) {
                int na = n0 + mt * 16 + 4 * g + r;
                qkvT[c * (NPTS * NA * DIM) + na * 64 + d] = acc[ni][r];
            }
        }
    }

    // ---- weight frag packing (blocks 0..71, one frag-set each) ----
    // set s: lane entry = 8 bf16 at pack[(s*64+lane)*8]
    // s<8: p2[mg][kt]; 8..40: w1[(hq*4+mg)*2+kt]; 40..72: w2[(hq*4+mg)*2+kt]
    if (blockIdx.x < 72 && t < 64) {
        int s = blockIdx.x;
        int c16p = t & 15, gp = t >> 4;
        const float* src;
        if (s < 8) {
            int mg = s >> 1, kt = s & 1;
            src = pos2 + (mg * 16 + c16p) * 64 + kt * 32 + gp * 8;
        } else if (s < 40) {
            int u = s - 8, hq = u >> 3, mg = (u >> 1) & 3, kt = u & 1;
            src = am1 + (hq * 64 + mg * 16 + c16p) * 64 + kt * 32 + gp * 8;
        } else {
            int u = s - 40, hq = u >> 3, mg = (u >> 1) & 3, kt = u & 1;
            src = am2 + (mg * 16 + c16p) * 256 + hq * 64 + kt * 32 + gp * 8;
        }
        unsigned short* dst = pack + (s * 64 + t) * 8;
        #pragma unroll
        for (int e = 0; e < 8; ++e) dst[e] = f2bfu(src[e]);
    }
}

// ---------------- kernel 2: KNN, one wave per point ----------------
__global__ __launch_bounds__(256) void knn_kernel(const float* __restrict__ xyz,
                                                  int* __restrict__ idxout) {
    __shared__ float px[NPTS], py[NPTS], pz[NPTS];
    const int t = threadIdx.x;
    for (int m = t; m < NPTS; m += 256) {
        px[m] = xyz[m];
        py[m] = xyz[NPTS + m];
        pz[m] = xyz[2 * NPTS + m];
    }
    __syncthreads();
    const int lane = t & 63, w = t >> 6;
    const int n = blockIdx.x * 4 + w;
    const float xn = px[n], yn = py[n], zn = pz[n];
    const float sqn = xn * xn + yn * yn + zn * zn;
    float dd[16]; int id[16];
    #pragma unroll
    for (int j = 0; j < 16; ++j) {
        int m = j * 64 + lane;
        float xm = px[m], ym = py[m], zm = pz[m];
        float sqm = xm * xm + ym * ym + zm * zm;
        float dot = xn * xm + yn * ym + zn * zm;
        dd[j] = sqn + sqm - 2.f * dot;
        id[j] = m;
    }
    for (int r = 0; r < KNN; ++r) {
        float bd = 1e30f; int bi = 0x7fffffff;
        #pragma unroll
        for (int j = 0; j < 16; ++j)
            if (dd[j] < bd || (dd[j] == bd && id[j] < bi)) { bd = dd[j]; bi = id[j]; }
        #pragma unroll
        for (int mask = 1; mask < 64; mask <<= 1) {
            float od = __shfl_xor(bd, mask);
            int oi = __shfl_xor(bi, mask);
            if (od < bd || (od == bd && oi < bi)) { bd = od; bi = oi; }
        }
        if (lane == 0) idxout[n * KNN + r] = bi;
        #pragma unroll
        for (int j = 0; j < 16; ++j)
            if (id[j] == bi) dd[j] = 1e30f;
    }
}

// ---------------- kernel 3: MFMA fused per-point attention (H in 4 K-quarter rounds) ----------------
__global__ __launch_bounds__(512, 4) void attn_main(const float* __restrict__ xyz,
                                                    const float* __restrict__ anchors,
                                                    const float* __restrict__ pos1,
                                                    const unsigned short* __restrict__ pack,
                                                    const float* __restrict__ qT,
                                                    const float* __restrict__ kT,
                                                    const float* __restrict__ vT,
                                                    const int* __restrict__ nn,
                                                    float* __restrict__ out) {
    __shared__ __align__(16) unsigned short XbT[NCOL][72];   // pe1T then X^T
    __shared__ __align__(16) unsigned short HqT[NCOL][72];   // H quarter ^T
    __shared__ float relb[KNN][3];
    __shared__ float ab[108];
    __shared__ int nidx[KNN];

    const int n = blockIdx.x, t = threadIdx.x;
    const int lane = t & 63, wave = t >> 6;
    const int c16 = lane & 15, g = lane >> 4;
    const int mg = wave >> 1, ng = wave & 1;

    if (t < 108) ab[t] = anchors[t];
    if (t < KNN) {
        int m = nn[n * KNN + t];
        nidx[t] = m;
        relb[t][0] = xyz[n] - xyz[m];
        relb[t][1] = xyz[NPTS + n] - xyz[NPTS + m];
        relb[t][2] = xyz[2 * NPTS + n] - xyz[2 * NPTS + m];
    }
    __syncthreads();

    // ---- step 1: pe1 = relu(P1 @ g) -> XbT ----
    {
        const float p10 = pos1[lane * 3 + 0], p11 = pos1[lane * 3 + 1], p12 = pos1[lane * 3 + 2];
        #pragma unroll
        for (int j = 0; j < 24; ++j) {
            int c = wave + 8 * j;
            int a = c >> 4, k = c & 15;
            float rx = relb[k][0], ry = relb[k][1], rz = relb[k][2];
            float g0 = ab[a * 9 + 0] * rx + ab[a * 9 + 1] * ry + ab[a * 9 + 2] * rz;
            float g1 = ab[a * 9 + 3] * rx + ab[a * 9 + 4] * ry + ab[a * 9 + 5] * rz;
            float g2 = ab[a * 9 + 6] * rx + ab[a * 9 + 7] * ry + ab[a * 9 + 8] * rz;
            float p = p10 * g0 + p11 * g1 + p12 * g2;
            XbT[c][lane] = f2bfu(p > 0.f ? p : 0.f);
        }
    }
    __syncthreads();

    const bf16x8* pk16 = (const bf16x8*)pack;
    const f32x4 zero4 = {0.f, 0.f, 0.f, 0.f};

    // ---- phase 0: pe = P2 @ pe1 ----
    f32x4 peacc[6] = {zero4, zero4, zero4, zero4, zero4, zero4};
    #pragma unroll
    for (int kt = 0; kt < 2; ++kt) {
        bf16x8 p2f = pk16[(mg * 2 + kt) * 64 + lane];
        #pragma unroll
        for (int i = 0; i < 6; ++i) {
            bf16x8 pb = *(const bf16x8*)&XbT[(ng * 6 + i) * 16 + c16][kt * 32 + g * 8];
            peacc[i] = __builtin_amdgcn_mfma_f32_16x16x32_bf16(p2f, pb, peacc[i], 0, 0, 0);
        }
    }

    // ---- step 3: vg in regs, X -> XbT ----
    float vgk[6][4], xreg[6][4];
    {
        const int m = nidx[c16];
        const int d0 = mg * 16 + 4 * g;
        #pragma unroll
        for (int i = 0; i < 6; ++i) {
            int a = ng * 6 + i;
            f32x4 qv = *(const f32x4*)&qT[(n * NA + a) * DIM + d0];
            f32x4 kg = *(const f32x4*)&kT[(m * NA + a) * DIM + d0];
            f32x4 vv = *(const f32x4*)&vT[(m * NA + a) * DIM + d0];
            #pragma unroll
            for (int r = 0; r < 4; ++r) {
                vgk[i][r] = vv[r] + peacc[i][r];
                xreg[i][r] = qv[r] - kg[r] + peacc[i][r];
            }
        }
    }
    __syncthreads();   // all phase-0 XbT reads done
    #pragma unroll
    for (int i = 0; i < 6; ++i) {
        int col = (ng * 6 + i) * 16 + c16;
        int row0 = mg * 16 + 4 * g;
        *(unsigned*)&XbT[col][row0]     = pk2(xreg[i][0], xreg[i][1]);
        *(unsigned*)&XbT[col][row0 + 2] = pk2(xreg[i][2], xreg[i][3]);
    }
    __syncthreads();

    // ---- 4 rounds: Hq = relu(W1[hq] @ X); sacc += W2[:,hq] @ Hq ----
    f32x4 sacc[6] = {zero4, zero4, zero4, zero4, zero4, zero4};
    for (int hq = 0; hq < 4; ++hq) {
        f32x4 hacc[6] = {zero4, zero4, zero4, zero4, zero4, zero4};
        #pragma unroll
        for (int kt = 0; kt < 2; ++kt) {
            bf16x8 w1f = pk16[(8 + (hq * 4 + mg) * 2 + kt) * 64 + lane];
            #pragma unroll
            for (int i = 0; i < 6; ++i) {
                bf16x8 xb = *(const bf16x8*)&XbT[(ng * 6 + i) * 16 + c16][kt * 32 + g * 8];
                hacc[i] = __builtin_amdgcn_mfma_f32_16x16x32_bf16(w1f, xb, hacc[i], 0, 0, 0);
            }
        }
        #pragma unroll
        for (int i = 0; i < 6; ++i) {
            int col = (ng * 6 + i) * 16 + c16;
            int hrow = mg * 16 + 4 * g;
            *(unsigned*)&HqT[col][hrow]     = pk2(fmaxf(hacc[i][0], 0.f), fmaxf(hacc[i][1], 0.f));
            *(unsigned*)&HqT[col][hrow + 2] = pk2(fmaxf(hacc[i][2], 0.f), fmaxf(hacc[i][3], 0.f));
        }
        __syncthreads();
        #pragma unroll
        for (int kt = 0; kt < 2; ++kt) {
            bf16x8 w2f = pk16[(40 + (hq * 4 + mg) * 2 + kt) * 64 + lane];
            #pragma unroll
            for (int i = 0; i < 6; ++i) {
                bf16x8 hb = *(const bf16x8*)&HqT[(ng * 6 + i) * 16 + c16][kt * 32 + g * 8];
                sacc[i] = __builtin_amdgcn_mfma_f32_16x16x32_bf16(w2f, hb, sacc[i], 0, 0, 0);
            }
        }
        __syncthreads();
    }

    // ---- epilogue: softmax over k (16-lane groups; |s| small -> no max shift), aggregate ----
    #pragma unroll
    for (int i = 0; i < 6; ++i) {
        int a = ng * 6 + i;
        #pragma unroll
        for (int r = 0; r < 4; ++r) {
            float e = __expf(sacc[i][r]);
            float den = e, num = e * vgk[i][r];
            #pragma unroll
            for (int mask = 1; mask < 16; mask <<= 1) {
                den += __shfl_xor(den, mask);
                num += __shfl_xor(num, mask);
            }
            if (c16 == 0) {
                int d = mg * 16 + 4 * g + r;
                out[(d * NPTS + n) * NA + a] = num / den;
            }
        }
    }
}

extern "C" void kernel_launch(void* const* d_in, const int* in_sizes, int n_in,
                              void* d_out, int out_size, void* d_ws, size_t ws_size,
                              hipStream_t stream) {
    const float* xyz     = (const float*)d_in[0];
    const float* feats   = (const float*)d_in[1];
    const float* anchors = (const float*)d_in[2];
    const float* to_qkv  = (const float*)d_in[3];
    const float* pos1    = (const float*)d_in[4];
    const float* pos2    = (const float*)d_in[5];
    const float* am1     = (const float*)d_in[6];
    const float* am2     = (const float*)d_in[7];
    float* out = (float*)d_out;

    float* ws = (float*)d_ws;
    const int seg = NPTS * NA * DIM;
    float* qT = ws;
    float* kT = ws + seg;
    float* vT = ws + 2 * seg;
    int* nn = (int*)(ws + 3 * seg);
    unsigned short* pack = (unsigned short*)(ws + 3 * seg + NPTS * KNN);

    qkv_kernel<<<256, 256, 0, stream>>>(feats, to_qkv, qT, pack, pos2, am1, am2);
    knn_kernel<<<256, 256, 0, stream>>>(xyz, nn);
    attn_main<<<NPTS, 512, 0, stream>>>(xyz, anchors, pos1, pack, qT, kT, vT, nn, out);
}

// Round 4
// 76.537 us; speedup vs baseline: 11.4882x; 1.2360x over previous
//
#include <hip/hip_runtime.h>

#define NPTS 1024
#define DIM 64
#define KNN 16
#define NA 12
#define NCOL 192              // (a,k) rows, idx = a*16 + k
#define XPAD 76               // u16 row stride (stride 38 words -> conflict-free b128 frags)

typedef __attribute__((ext_vector_type(8))) short bf16x8;
typedef __attribute__((ext_vector_type(4))) float f32x4;

static __device__ inline unsigned short f2bfu(float x) {
    __bf16 b = (__bf16)x;                       // hw v_cvt (RNE)
    return __builtin_bit_cast(unsigned short, b);
}
static __device__ inline bf16x8 load8_cvt(const float* p) {
    f32x4 u = *(const f32x4*)p;
    f32x4 v = *(const f32x4*)(p + 4);
    bf16x8 r;
    r[0] = (short)f2bfu(u[0]); r[1] = (short)f2bfu(u[1]); r[2] = (short)f2bfu(u[2]); r[3] = (short)f2bfu(u[3]);
    r[4] = (short)f2bfu(v[0]); r[5] = (short)f2bfu(v[1]); r[6] = (short)f2bfu(v[2]); r[7] = (short)f2bfu(v[3]);
    return r;
}

// ---------------- prep kernel: qkv^T MFMA + weight frag packing + KNN ----------------
__global__ __launch_bounds__(256) void prep_kernel(const float* __restrict__ feats,
                                                   const float* __restrict__ to_qkv,
                                                   float* __restrict__ qkvT,
                                                   unsigned short* __restrict__ pack,
                                                   const float* __restrict__ pos2,
                                                   const float* __restrict__ am1,
                                                   const float* __restrict__ am2,
                                                   const float* __restrict__ xyz,
                                                   int* __restrict__ idxout) {
    __shared__ unsigned short XT[48][72];   // feats^T [na][i] bf16
    __shared__ float px[NPTS], py[NPTS], pz[NPTS];
    const int t = threadIdx.x;
    const int n0 = blockIdx.x * 48;

    // ---- weight frag packing (blocks 0..71, one frag-set each) ----
    if (blockIdx.x < 72 && t < 64) {
        int s = blockIdx.x;
        int c16p = t & 15, gp = t >> 4;
        const float* src;
        if (s < 8) {
            int nt = s >> 1, kt = s & 1;
            src = pos2 + (nt * 16 + c16p) * 64 + kt * 32 + gp * 8;
        } else if (s < 40) {
            int u = s - 8, hq = u >> 3, nt = (u >> 1) & 3, kt = u & 1;
            src = am1 + (hq * 64 + nt * 16 + c16p) * 64 + kt * 32 + gp * 8;
        } else {
            int u = s - 40, hq = u >> 3, nt = (u >> 1) & 3, kt = u & 1;
            src = am2 + (nt * 16 + c16p) * 256 + hq * 64 + kt * 32 + gp * 8;
        }
        unsigned short* dst = pack + (s * 64 + t) * 8;
        #pragma unroll
        for (int e = 0; e < 8; ++e) dst[e] = f2bfu(src[e]);
    }

    // ---- stage ----
    for (int m = t; m < NPTS; m += 256) {
        px[m] = xyz[m];
        py[m] = xyz[NPTS + m];
        pz[m] = xyz[2 * NPTS + m];
    }
    for (int e = t; e < 48 * 64; e += 256) {
        int c = e % 48, i = e / 48;
        XT[c][i] = f2bfu(feats[i * (NPTS * NA) + n0 + c]);
    }
    __syncthreads();

    const int lane = t & 63, w = t >> 6, c16 = lane & 15, g = lane >> 4;

    // ---- qkv: D[na][cd] = feats^T @ to_qkv^T ----
    {
        bf16x8 bfr[3][2];
        #pragma unroll
        for (int ni = 0; ni < 3; ++ni)
            #pragma unroll
            for (int kt = 0; kt < 2; ++kt) {
                int cd = (w * 3 + ni) * 16 + c16;
                bfr[ni][kt] = load8_cvt(to_qkv + cd * 64 + kt * 32 + g * 8);
            }
        const f32x4 zero4 = {0.f, 0.f, 0.f, 0.f};
        #pragma unroll
        for (int mt = 0; mt < 3; ++mt) {
            f32x4 acc[3] = {zero4, zero4, zero4};
            #pragma unroll
            for (int kt = 0; kt < 2; ++kt) {
                bf16x8 af = *(const bf16x8*)&XT[mt * 16 + c16][kt * 32 + g * 8];
                #pragma unroll
                for (int ni = 0; ni < 3; ++ni)
                    acc[ni] = __builtin_amdgcn_mfma_f32_16x16x32_bf16(af, bfr[ni][kt], acc[ni], 0, 0, 0);
            }
            #pragma unroll
            for (int ni = 0; ni < 3; ++ni) {
                int cd = (w * 3 + ni) * 16 + c16;
                int c = cd >> 6, d = cd & 63;
                #pragma unroll
                for (int r = 0; r < 4; ++r) {
                    int na = n0 + mt * 16 + 4 * g + r;
                    qkvT[c * (NPTS * NA * DIM) + na * 64 + d] = acc[ni][r];
                }
            }
        }
    }

    // ---- knn: one wave per point, 4 points per block ----
    {
        const int n = blockIdx.x * 4 + w;
        const float xn = px[n], yn = py[n], zn = pz[n];
        const float sqn = xn * xn + yn * yn + zn * zn;
        float dd[16]; int id[16];
        #pragma unroll
        for (int j = 0; j < 16; ++j) {
            int m = j * 64 + lane;
            float xm = px[m], ym = py[m], zm = pz[m];
            float sqm = xm * xm + ym * ym + zm * zm;
            float dot = xn * xm + yn * ym + zn * zm;
            dd[j] = sqn + sqm - 2.f * dot;
            id[j] = m;
        }
        for (int r = 0; r < KNN; ++r) {
            float bd = 1e30f; int bi = 0x7fffffff;
            #pragma unroll
            for (int j = 0; j < 16; ++j)
                if (dd[j] < bd || (dd[j] == bd && id[j] < bi)) { bd = dd[j]; bi = id[j]; }
            #pragma unroll
            for (int mask = 1; mask < 64; mask <<= 1) {
                float od = __shfl_xor(bd, mask);
                int oi = __shfl_xor(bi, mask);
                if (od < bd || (od == bd && oi < bi)) { bd = od; bi = oi; }
            }
            if (lane == 0) idxout[n * KNN + r] = bi;
            #pragma unroll
            for (int j = 0; j < 16; ++j)
                if (id[j] == bi) dd[j] = 1e30f;
        }
    }
}

// ---------------- attn kernel: S^T orientation, activations = A-operand ----------------
// 8 waves: mw = wave&3 -> m-tiles {mw, mw+4, mw+8}; nw = wave>>2 -> n-tiles {2nw, 2nw+1}.
// C layout: lane(c16,g) reg r holds D[(a=mt, k=4g+r)][out = nt*16+c16].
__global__ __launch_bounds__(512, 4) void attn_main(const float* __restrict__ xyz,
                                                    const float* __restrict__ anchors,
                                                    const float* __restrict__ pos1,
                                                    const unsigned short* __restrict__ pack,
                                                    const float* __restrict__ qT,
                                                    const float* __restrict__ kT,
                                                    const float* __restrict__ vT,
                                                    const int* __restrict__ nn,
                                                    float* __restrict__ out) {
    __shared__ __align__(16) unsigned short XbT[NCOL][XPAD];   // pe1^T then X^T [(a,k)][h/d]
    __shared__ __align__(16) unsigned short HqT[NCOL][XPAD];   // H-quarter^T [(a,k)][h]
    __shared__ float relb[KNN][3];
    __shared__ float ab[108];
    __shared__ float gbuf[3][NCOL];
    __shared__ int nidx[KNN];

    const int n = blockIdx.x, t = threadIdx.x;
    const int lane = t & 63, wave = t >> 6;
    const int c16 = lane & 15, g = lane >> 4;
    const int mw = wave & 3;
    const int nw = wave >> 2;

    if (t < 108) ab[t] = anchors[t];
    if (t < KNN) {
        int m = nn[n * KNN + t];
        nidx[t] = m;
        relb[t][0] = xyz[n] - xyz[m];
        relb[t][1] = xyz[NPTS + n] - xyz[NPTS + m];
        relb[t][2] = xyz[2 * NPTS + n] - xyz[2 * NPTS + m];
    }
    __syncthreads();

    // ---- step 0: G[row][col] = (A_a @ rel_k)[row] ----
    for (int e = t; e < 3 * NCOL; e += 512) {
        int row = e / NCOL, col = e % NCOL;
        int a = col >> 4, k = col & 15;
        gbuf[row][col] = ab[a * 9 + row * 3 + 0] * relb[k][0]
                       + ab[a * 9 + row * 3 + 1] * relb[k][1]
                       + ab[a * 9 + row * 3 + 2] * relb[k][2];
    }
    __syncthreads();

    // ---- step 1: pe1^T = relu(P1 @ G)^T -> XbT ----
    {
        const float p10 = pos1[lane * 3 + 0], p11 = pos1[lane * 3 + 1], p12 = pos1[lane * 3 + 2];
        #pragma unroll
        for (int j = 0; j < 24; ++j) {
            int col = wave + 8 * j;
            float p = p10 * gbuf[0][col] + p11 * gbuf[1][col] + p12 * gbuf[2][col];
            XbT[col][lane] = f2bfu(p > 0.f ? p : 0.f);
        }
    }
    __syncthreads();

    const bf16x8* pk16 = (const bf16x8*)pack;
    const f32x4 zero4 = {0.f, 0.f, 0.f, 0.f};

    // ---- phase 0: pe^T = pe1^T @ P2^T ----
    f32x4 peacc[6] = {zero4, zero4, zero4, zero4, zero4, zero4};
    #pragma unroll
    for (int kt = 0; kt < 2; ++kt) {
        bf16x8 b0 = pk16[((2 * nw + 0) * 2 + kt) * 64 + lane];
        bf16x8 b1 = pk16[((2 * nw + 1) * 2 + kt) * 64 + lane];
        #pragma unroll
        for (int mi = 0; mi < 3; ++mi) {
            bf16x8 af = *(const bf16x8*)&XbT[(mw + 4 * mi) * 16 + c16][kt * 32 + g * 8];
            peacc[mi * 2 + 0] = __builtin_amdgcn_mfma_f32_16x16x32_bf16(af, b0, peacc[mi * 2 + 0], 0, 0, 0);
            peacc[mi * 2 + 1] = __builtin_amdgcn_mfma_f32_16x16x32_bf16(af, b1, peacc[mi * 2 + 1], 0, 0, 0);
        }
    }

    // ---- step 3: X = q - k_g + pe (regs), vg = v_g + pe (stays in regs!) ----
    float vgk[6][4], xreg[6][4];
    {
        const int m0 = nidx[4 * g + 0], m1 = nidx[4 * g + 1];
        const int m2 = nidx[4 * g + 2], m3 = nidx[4 * g + 3];
        #pragma unroll
        for (int mi = 0; mi < 3; ++mi) {
            int a = mw + 4 * mi;
            #pragma unroll
            for (int ni = 0; ni < 2; ++ni) {
                int tile = mi * 2 + ni;
                int d = (2 * nw + ni) * 16 + c16;
                float qv = qT[(n * NA + a) * DIM + d];
                int b0 = (m0 * NA + a) * DIM + d, b1 = (m1 * NA + a) * DIM + d;
                int b2 = (m2 * NA + a) * DIM + d, b3 = (m3 * NA + a) * DIM + d;
                xreg[tile][0] = qv - kT[b0] + peacc[tile][0]; vgk[tile][0] = vT[b0] + peacc[tile][0];
                xreg[tile][1] = qv - kT[b1] + peacc[tile][1]; vgk[tile][1] = vT[b1] + peacc[tile][1];
                xreg[tile][2] = qv - kT[b2] + peacc[tile][2]; vgk[tile][2] = vT[b2] + peacc[tile][2];
                xreg[tile][3] = qv - kT[b3] + peacc[tile][3]; vgk[tile][3] = vT[b3] + peacc[tile][3];
            }
        }
    }
    __syncthreads();   // phase-0 XbT reads complete before overwrite
    #pragma unroll
    for (int mi = 0; mi < 3; ++mi)
        #pragma unroll
        for (int ni = 0; ni < 2; ++ni) {
            int tile = mi * 2 + ni;
            int col = (2 * nw + ni) * 16 + c16;
            #pragma unroll
            for (int r = 0; r < 4; ++r)
                XbT[(mw + 4 * mi) * 16 + 4 * g + r][col] = f2bfu(xreg[tile][r]);
        }
    __syncthreads();

    // ---- 4 rounds: Hq^T = relu(X^T @ W1q^T); S^T += Hq^T @ W2q^T ----
    f32x4 sacc[6] = {zero4, zero4, zero4, zero4, zero4, zero4};
    for (int hq = 0; hq < 4; ++hq) {
        f32x4 hacc[6] = {zero4, zero4, zero4, zero4, zero4, zero4};
        #pragma unroll
        for (int kt = 0; kt < 2; ++kt) {
            bf16x8 b0 = pk16[(8 + (hq * 4 + 2 * nw + 0) * 2 + kt) * 64 + lane];
            bf16x8 b1 = pk16[(8 + (hq * 4 + 2 * nw + 1) * 2 + kt) * 64 + lane];
            #pragma unroll
            for (int mi = 0; mi < 3; ++mi) {
                bf16x8 af = *(const bf16x8*)&XbT[(mw + 4 * mi) * 16 + c16][kt * 32 + g * 8];
                hacc[mi * 2 + 0] = __builtin_amdgcn_mfma_f32_16x16x32_bf16(af, b0, hacc[mi * 2 + 0], 0, 0, 0);
                hacc[mi * 2 + 1] = __builtin_amdgcn_mfma_f32_16x16x32_bf16(af, b1, hacc[mi * 2 + 1], 0, 0, 0);
            }
        }
        #pragma unroll
        for (int mi = 0; mi < 3; ++mi)
            #pragma unroll
            for (int ni = 0; ni < 2; ++ni) {
                int tile = mi * 2 + ni;
                int col = (2 * nw + ni) * 16 + c16;
                #pragma unroll
                for (int r = 0; r < 4; ++r)
                    HqT[(mw + 4 * mi) * 16 + 4 * g + r][col] = f2bfu(fmaxf(hacc[tile][r], 0.f));
            }
        __syncthreads();
        #pragma unroll
        for (int kt = 0; kt < 2; ++kt) {
            bf16x8 b0 = pk16[(40 + hq * 8 + (2 * nw + 0) * 2 + kt) * 64 + lane];
            bf16x8 b1 = pk16[(40 + hq * 8 + (2 * nw + 1) * 2 + kt) * 64 + lane];
            #pragma unroll
            for (int mi = 0; mi < 3; ++mi) {
                bf16x8 af = *(const bf16x8*)&HqT[(mw + 4 * mi) * 16 + c16][kt * 32 + g * 8];
                sacc[mi * 2 + 0] = __builtin_amdgcn_mfma_f32_16x16x32_bf16(af, b0, sacc[mi * 2 + 0], 0, 0, 0);
                sacc[mi * 2 + 1] = __builtin_amdgcn_mfma_f32_16x16x32_bf16(af, b1, sacc[mi * 2 + 1], 0, 0, 0);
            }
        }
        __syncthreads();
    }

    // ---- epilogue: softmax over k = (4g+r); reg-sum over r, 2 shuffles over g ----
    #pragma unroll
    for (int mi = 0; mi < 3; ++mi) {
        int a = mw + 4 * mi;
        #pragma unroll
        for (int ni = 0; ni < 2; ++ni) {
            int tile = mi * 2 + ni;
            int d = (2 * nw + ni) * 16 + c16;
            float e0 = __expf(sacc[tile][0]);
            float e1 = __expf(sacc[tile][1]);
            float e2 = __expf(sacc[tile][2]);
            float e3 = __expf(sacc[tile][3]);
            float den = (e0 + e1) + (e2 + e3);
            float num = (e0 * vgk[tile][0] + e1 * vgk[tile][1]) + (e2 * vgk[tile][2] + e3 * vgk[tile][3]);
            den += __shfl_xor(den, 16); num += __shfl_xor(num, 16);
            den += __shfl_xor(den, 32); num += __shfl_xor(num, 32);
            if (g == 0)
                out[(d * NPTS + n) * NA + a] = num / den;
        }
    }
}

extern "C" void kernel_launch(void* const* d_in, const int* in_sizes, int n_in,
                              void* d_out, int out_size, void* d_ws, size_t ws_size,
                              hipStream_t stream) {
    const float* xyz     = (const float*)d_in[0];
    const float* feats   = (const float*)d_in[1];
    const float* anchors = (const float*)d_in[2];
    const float* to_qkv  = (const float*)d_in[3];
    const float* pos1    = (const float*)d_in[4];
    const float* pos2    = (const float*)d_in[5];
    const float* am1     = (const float*)d_in[6];
    const float* am2     = (const float*)d_in[7];
    float* out = (float*)d_out;

    float* ws = (float*)d_ws;
    const int seg = NPTS * NA * DIM;
    float* qT = ws;
    float* kT = ws + seg;
    float* vT = ws + 2 * seg;
    int* nn = (int*)(ws + 3 * seg);
    unsigned short* pack = (unsigned short*)(ws + 3 * seg + NPTS * KNN);

    prep_kernel<<<256, 256, 0, stream>>>(feats, to_qkv, qT, pack, pos2, am1, am2, xyz, nn);
    attn_main<<<NPTS, 512, 0, stream>>>(xyz, anchors, pos1, pack, qT, kT, vT, nn, out);
}